// Round 4
// baseline (244.778 us; speedup 1.0000x reference)
//
#include <hip/hip_runtime.h>

#define SEQ 4096
#define DM  768
#define NH  12
#define DK  64

typedef __bf16 bf16_t;
typedef bf16_t bf16x8 __attribute__((ext_vector_type(8)));
typedef bf16_t bf16x4 __attribute__((ext_vector_type(4)));
typedef float  f32x4  __attribute__((ext_vector_type(4)));
typedef short  s16x4  __attribute__((ext_vector_type(4)));

#define LOG2E 1.44269504088896340736f
#define SM_C2 23.0831207f   // 16 * LOG2E; LOG2E folded into K pre-scale

static __device__ inline f32x4 mfma16x16x16_bf16(bf16x4 a, bf16x4 b, f32x4 c) {
#if __has_builtin(__builtin_amdgcn_mfma_f32_16x16x16_bf16)
    return __builtin_amdgcn_mfma_f32_16x16x16_bf16(a, b, c, 0, 0, 0);
#else
    return __builtin_amdgcn_mfma_f32_16x16x16bf16_1k(
        __builtin_bit_cast(s16x4, a), __builtin_bit_cast(s16x4, b), c, 0, 0, 0);
#endif
}

// async global->LDS, 16 B per lane; LDS dest = wave-uniform base + lane*16
static __device__ __forceinline__ void gl_lds16(const bf16_t* g, bf16_t* l) {
    __builtin_amdgcn_global_load_lds(
        (const __attribute__((address_space(1))) void*)g,
        (__attribute__((address_space(3))) void*)l, 16, 0, 0);
}

// ---------------------------------------------------------------------------
// fp32 -> bf16 bulk convert: x (SEQ*DM) then Wq,Wk,Wv,Wo (DM*DM each)
// ---------------------------------------------------------------------------
__global__ __launch_bounds__(256) void cvt_bf16(
    const float* __restrict__ x,  const float* __restrict__ Wq,
    const float* __restrict__ Wk, const float* __restrict__ Wv,
    const float* __restrict__ Wo,
    bf16_t* __restrict__ xb, bf16_t* __restrict__ Wb)
{
    const int NXV = SEQ * DM / 4;
    const int NWV = DM * DM / 4;
    int i4 = blockIdx.x * 256 + threadIdx.x;
    const float* src; bf16_t* dst; int off;
    if (i4 < NXV) { src = x; dst = xb; off = i4; }
    else {
        int j = i4 - NXV;
        int w = j / NWV, jj = j - w * NWV;
        src = (w == 0) ? Wq : (w == 1) ? Wk : (w == 2) ? Wv : Wo;
        dst = Wb + (size_t)w * DM * DM;
        off = jj;
    }
    float4 v = *(const float4*)&src[(size_t)off * 4];
    bf16x4 t;
    t[0] = (bf16_t)v.x; t[1] = (bf16_t)v.y; t[2] = (bf16_t)v.z; t[3] = (bf16_t)v.w;
    *(bf16x4*)&dst[(size_t)off * 4] = t;
}

// ---------------------------------------------------------------------------
// m97-style GEMM (BK=64, global_load_lds 16B, XOR-chunk swizzle).
// C[M,N] = A[M,K](bf16)*W[N,K]^T(bf16)+bias. z = {Q,K,V}; K pre-scaled by
// (1/8)*LOG2E (softmax done in exp2 domain); V stored transposed [DM][SEQ].
// ---------------------------------------------------------------------------
__global__ __launch_bounds__(256) void gemm_qkv2(
    const bf16_t* __restrict__ A, const bf16_t* __restrict__ Wb,
    const float* __restrict__ bq, const float* __restrict__ bk,
    const float* __restrict__ bv,
    bf16_t* __restrict__ Qb, bf16_t* __restrict__ Kb, bf16_t* __restrict__ Vbt)
{
    const int z = blockIdx.z;
    const bf16_t* W = Wb + (size_t)z * DM * DM;
    const float* bias = (z == 0) ? bq : (z == 1) ? bk : bv;

    __shared__ bf16_t As[128][64];   // unpadded (global_load_lds) + swizzle
    __shared__ bf16_t Bs[128][64];

    const int tid  = threadIdx.x;
    const int wave = tid >> 6;
    const int lane = tid & 63;
    const int wm   = wave & 1, wn = wave >> 1;
    const int lrow = lane & 15;
    const int quad = lane >> 4;
    const int row0 = blockIdx.x * 128;
    const int col0 = blockIdx.y * 128;

    const int srow   = lane >> 3;            // 0..7 within 8-row load group
    const int schunk = (lane & 7) ^ srow;    // swizzled source chunk
    const int swz    = lrow & 7;             // frag-read swizzle key

    f32x4 acc[4][4];
    #pragma unroll
    for (int i = 0; i < 4; i++)
        #pragma unroll
        for (int j = 0; j < 4; j++)
            acc[i][j] = (f32x4){0.f, 0.f, 0.f, 0.f};

    for (int k0 = 0; k0 < DM; k0 += 64) {
        __syncthreads();
        #pragma unroll
        for (int u = 0; u < 4; u++) {
            int R0 = wave * 32 + u * 8;
            gl_lds16(&A[(size_t)(row0 + R0 + srow) * DM + k0 + schunk * 8],
                     &As[R0][0]);
            gl_lds16(&W[(size_t)(col0 + R0 + srow) * DM + k0 + schunk * 8],
                     &Bs[R0][0]);
        }
        __syncthreads();   // compiler drains vmcnt here

        #pragma unroll
        for (int s = 0; s < 2; s++) {
            bf16x8 af[4], bfr[4];
            #pragma unroll
            for (int mt = 0; mt < 4; mt++)
                af[mt] = *(const bf16x8*)
                    &As[wm * 64 + mt * 16 + lrow][(((s << 2) | quad) ^ swz) * 8];
            #pragma unroll
            for (int nt = 0; nt < 4; nt++)
                bfr[nt] = *(const bf16x8*)
                    &Bs[wn * 64 + nt * 16 + lrow][(((s << 2) | quad) ^ swz) * 8];
            #pragma unroll
            for (int mt = 0; mt < 4; mt++)
                #pragma unroll
                for (int nt = 0; nt < 4; nt++)
                    acc[mt][nt] = __builtin_amdgcn_mfma_f32_16x16x32_bf16(
                        af[mt], bfr[nt], acc[mt][nt], 0, 0, 0);
        }
    }

    if (z == 2) {          // V transposed [DM][SEQ]
        #pragma unroll
        for (int nt = 0; nt < 4; nt++) {
            int col = col0 + wn * 64 + nt * 16 + lrow;
            float bvv = bias[col];
            #pragma unroll
            for (int mt = 0; mt < 4; mt++) {
                int row = row0 + wm * 64 + mt * 16 + quad * 4;
                bf16x4 t;
                #pragma unroll
                for (int r = 0; r < 4; r++) t[r] = (bf16_t)(acc[mt][nt][r] + bvv);
                *(bf16x4*)&Vbt[(size_t)col * SEQ + row] = t;
            }
        }
    } else {
        bf16_t* Cout = (z == 0) ? Qb : Kb;
        // K: fold 1/sqrt(dk) AND log2(e) so flash softmax is exp2(sc - C)
        float scale = (z == 1) ? (0.125f * LOG2E) : 1.0f;
        #pragma unroll
        for (int nt = 0; nt < 4; nt++) {
            int col = col0 + wn * 64 + nt * 16 + lrow;
            float bvv = bias[col];
            #pragma unroll
            for (int mt = 0; mt < 4; mt++) {
                #pragma unroll
                for (int r = 0; r < 4; r++) {
                    int row = row0 + wm * 64 + mt * 16 + quad * 4 + r;
                    Cout[(size_t)row * DM + col] =
                        (bf16_t)((acc[mt][nt][r] + bvv) * scale);
                }
            }
        }
    }
}

// ---------------------------------------------------------------------------
// out[M,N](f32) = A[M,K](bf16)*W[N,K]^T(bf16)+bias. Tile 128x64 (384 blocks).
// ---------------------------------------------------------------------------
__global__ __launch_bounds__(256) void gemm_out2(
    const bf16_t* __restrict__ A, const bf16_t* __restrict__ W,
    const float* __restrict__ bias, float* __restrict__ C)
{
    __shared__ bf16_t As[128][64];
    __shared__ bf16_t Bs[64][64];

    const int tid  = threadIdx.x;
    const int wave = tid >> 6;
    const int lane = tid & 63;
    const int wm   = wave & 1, wn = wave >> 1;
    const int lrow = lane & 15;
    const int quad = lane >> 4;
    const int row0 = blockIdx.x * 128;
    const int col0 = blockIdx.y * 64;

    const int srow   = lane >> 3;
    const int schunk = (lane & 7) ^ srow;
    const int swz    = lrow & 7;

    f32x4 acc[4][2];
    #pragma unroll
    for (int i = 0; i < 4; i++)
        #pragma unroll
        for (int j = 0; j < 2; j++)
            acc[i][j] = (f32x4){0.f, 0.f, 0.f, 0.f};

    for (int k0 = 0; k0 < DM; k0 += 64) {
        __syncthreads();
        #pragma unroll
        for (int u = 0; u < 4; u++) {
            int R0 = wave * 32 + u * 8;
            gl_lds16(&A[(size_t)(row0 + R0 + srow) * DM + k0 + schunk * 8],
                     &As[R0][0]);
        }
        #pragma unroll
        for (int u = 0; u < 2; u++) {
            int R0 = wave * 16 + u * 8;
            gl_lds16(&W[(size_t)(col0 + R0 + srow) * DM + k0 + schunk * 8],
                     &Bs[R0][0]);
        }
        __syncthreads();

        #pragma unroll
        for (int s = 0; s < 2; s++) {
            bf16x8 af[4], bfr[2];
            #pragma unroll
            for (int mt = 0; mt < 4; mt++)
                af[mt] = *(const bf16x8*)
                    &As[wm * 64 + mt * 16 + lrow][(((s << 2) | quad) ^ swz) * 8];
            #pragma unroll
            for (int nt = 0; nt < 2; nt++)
                bfr[nt] = *(const bf16x8*)
                    &Bs[wn * 32 + nt * 16 + lrow][(((s << 2) | quad) ^ swz) * 8];
            #pragma unroll
            for (int mt = 0; mt < 4; mt++)
                #pragma unroll
                for (int nt = 0; nt < 2; nt++)
                    acc[mt][nt] = __builtin_amdgcn_mfma_f32_16x16x32_bf16(
                        af[mt], bfr[nt], acc[mt][nt], 0, 0, 0);
        }
    }

    #pragma unroll
    for (int nt = 0; nt < 2; nt++) {
        int col = col0 + wn * 32 + nt * 16 + lrow;
        float bvv = bias[col];
        #pragma unroll
        for (int mt = 0; mt < 4; mt++) {
            #pragma unroll
            for (int r = 0; r < 4; r++) {
                int row = row0 + wm * 64 + mt * 16 + quad * 4 + r;
                C[(size_t)row * DM + col] = acc[mt][nt][r] + bvv;
            }
        }
    }
}

// ---------------------------------------------------------------------------
// Flash attention v6: LDS-traffic-halving version.
//
// Diagnosis (r3): LDS pipe ~80% busy (24 KB LDS traffic per wave-iter x
// ~390 wave-iters/CU at 85 B/cyc + 6.39M conflict cycles) -- all schedule
// variants tied at ~70 us. Fix: each K/V fragment read feeds TWO 16-row
// q-chunks (32 q-rows/wave) -> wave-iters halve (100K -> 50.7K), LDS
// traffic per unit work halves.
//
// Same body as v4 (correctness-verified) but with plain
// __launch_bounds__(256): v4's (256,4) forced 64 VGPR onto a ~110-VGPR
// body -> scratch spill (FETCH/WRITE ~450 MB, 4.6% MfmaUtil). Natural
// allocation ~112-128 VGPR -> 4 waves/SIMD; LDS 32 KB.
// Longest-first dispatch (f = 143 - blockIdx.x) for LPT tail packing.
// ---------------------------------------------------------------------------
__global__ __launch_bounds__(256) void flash_split6(
    const bf16_t* __restrict__ Qb, const bf16_t* __restrict__ Kb,
    const bf16_t* __restrict__ Vbt,
    float* __restrict__ Oacc /* [NH][DK][SEQ] */,
    float* __restrict__ Lacc /* [NH][SEQ] */)
{
    const int h = blockIdx.z;
    const int f = 143 - blockIdx.x;     // longest-first (LPT)
    int g = 0;                          // staircase group = qi/4
    while (f >= 2 * (g + 1) * (g + 2)) g++;
    const int rem = f - 2 * g * (g + 1);
    const int qs  = rem / (g + 1);
    const int seg = rem - qs * (g + 1);
    const int qi  = g * 4 + qs;         // q-tile (128 rows)
    const int q0  = qi << 7;
    const int kt0    = seg << 3;        // first k-tile (64 keys each)
    const int ktlast = min(kt0 + 7, 2 * qi + 1);

    const int tid  = threadIdx.x;
    const int wave = tid >> 6;          // 0..3, owns rows q0+wave*32 .. +31
    const int lane = tid & 63;
    const int lrow = lane & 15;
    const int quad = lane >> 4;
    const int swz  = lrow & 7;

    __shared__ bf16_t Ks[2][64][64];    // [key][kdim], XOR-swizzled chunks
    __shared__ bf16_t Vs[2][64][64];    // [d][key],   XOR-swizzled chunks

    const int rbase = q0 + wave * 32;   // this wave's first q row
    bf16x8 qf[2][2];                    // [chunk][khalf]
    #pragma unroll
    for (int c = 0; c < 2; c++)
        #pragma unroll
        for (int s = 0; s < 2; s++)
            qf[c][s] = *(const bf16x8*)
                &Qb[(size_t)(rbase + c * 16 + lrow) * DM + h * DK + s * 32 + quad * 8];

    f32x4 oT0[4], oT1[4];
    #pragma unroll
    for (int dt = 0; dt < 4; dt++) {
        oT0[dt] = (f32x4){0.f, 0.f, 0.f, 0.f};
        oT1[dt] = (f32x4){0.f, 0.f, 0.f, 0.f};
    }
    float l0 = 0.f, l1 = 0.f;

    // staging: wave w stages K rows w*16..+15 and V d-rows w*16..+15
    // (two 8-row 1KB groups each); source chunk pre-swizzled.
    const int srow8 = lane >> 3;              // 0..7
    const int schnk = (lane & 7) ^ srow8;     // swizzled source chunk

    #define STAGE(bb, kk)                                                      \
        do {                                                                   \
            size_t ko_ = (size_t)(kk) << 6;                                    \
            _Pragma("unroll")                                                  \
            for (int r_ = 0; r_ < 2; r_++) {                                   \
                int row_ = wave * 16 + r_ * 8;                                 \
                gl_lds16(&Kb[(ko_ + row_ + srow8) * DM + h * DK + schnk * 8],  \
                         &Ks[bb][row_][0]);                                    \
                gl_lds16(&Vbt[(size_t)(h * DK + row_ + srow8) * SEQ + ko_ +    \
                              schnk * 8],                                      \
                         &Vs[bb][row_][0]);                                    \
            }                                                                  \
        } while (0)

    STAGE(0, kt0);

    for (int kt = kt0; kt <= ktlast; kt++) {
        const int b = kt & 1;
        __syncthreads();                 // drains own vmcnt -> buf b ready
        if (kt < ktlast) STAGE(b ^ 1, kt + 1);   // latency hides under compute

        const int kbase = kt << 6;
        const bool a0 = (kbase <= rbase + 15);   // lower 16-row chunk active
        const bool a1 = (kbase <= rbase + 31);   // upper chunk active
        if (!a1) continue;                        // staging already issued

        // QK^T: each kf fragment feeds BOTH chunks' MFMAs
        f32x4 s0[4], s1[4];
        #pragma unroll
        for (int mt = 0; mt < 4; mt++) {
            s0[mt] = (f32x4){0.f, 0.f, 0.f, 0.f};
            s1[mt] = (f32x4){0.f, 0.f, 0.f, 0.f};
        }
        #pragma unroll
        for (int s = 0; s < 2; s++)
            #pragma unroll
            for (int mt = 0; mt < 4; mt++) {
                bf16x8 kf = *(const bf16x8*)
                    &Ks[b][mt * 16 + lrow][(((s << 2) | quad) ^ swz) * 8];
                if (a0)
                    s0[mt] = __builtin_amdgcn_mfma_f32_16x16x32_bf16(
                        kf, qf[0][s], s0[mt], 0, 0, 0);
                s1[mt] = __builtin_amdgcn_mfma_f32_16x16x32_bf16(
                    kf, qf[1][s], s1[mt], 0, 0, 0);
            }

        // causal mask (only on tiles overlapping each chunk's diagonal)
        if (kbase + 63 > rbase) {
            int qg0 = rbase + lrow;
            #pragma unroll
            for (int mt = 0; mt < 4; mt++)
                #pragma unroll
                for (int rr = 0; rr < 4; rr++)
                    if (kbase + mt * 16 + quad * 4 + rr > qg0)
                        s0[mt][rr] = -1e30f;
        }
        if (kbase + 63 > rbase + 16) {
            int qg1 = rbase + 16 + lrow;
            #pragma unroll
            for (int mt = 0; mt < 4; mt++)
                #pragma unroll
                for (int rr = 0; rr < 4; rr++)
                    if (kbase + mt * 16 + quad * 4 + rr > qg1)
                        s1[mt][rr] = -1e30f;
        }

        // softmax numerators (fixed shift, exp2 domain)
        bf16x4 pf0[4], pf1[4];
        if (a0) {
            float rsum = 0.f;
            #pragma unroll
            for (int mt = 0; mt < 4; mt++) {
                bf16x4 t;
                #pragma unroll
                for (int rr = 0; rr < 4; rr++) {
                    float p = __builtin_amdgcn_exp2f(s0[mt][rr] - SM_C2);
                    rsum += p;
                    t[rr] = (bf16_t)p;
                }
                pf0[mt] = t;
            }
            l0 += rsum;
        }
        {
            float rsum = 0.f;
            #pragma unroll
            for (int mt = 0; mt < 4; mt++) {
                bf16x4 t;
                #pragma unroll
                for (int rr = 0; rr < 4; rr++) {
                    float p = __builtin_amdgcn_exp2f(s1[mt][rr] - SM_C2);
                    rsum += p;
                    t[rr] = (bf16_t)p;
                }
                pf1[mt] = t;
            }
            l1 += rsum;
        }

        // PV: each vf fragment feeds BOTH chunks' MFMAs
        #pragma unroll
        for (int dt = 0; dt < 4; dt++)
            #pragma unroll
            for (int kb = 0; kb < 4; kb++) {
                int c16 = (kb * 2 + (quad >> 1)) ^ swz;
                bf16x4 vf = *(const bf16x4*)
                    &Vs[b][dt * 16 + lrow][c16 * 8 + (quad & 1) * 4];
                if (a0) oT0[dt] = mfma16x16x16_bf16(vf, pf0[kb], oT0[dt]);
                oT1[dt] = mfma16x16x16_bf16(vf, pf1[kb], oT1[dt]);
            }
    }
    #undef STAGE

    #pragma unroll
    for (int dt = 0; dt < 4; dt++)
        #pragma unroll
        for (int rr = 0; rr < 4; rr++) {
            int d = dt * 16 + quad * 4 + rr;
            atomicAdd(&Oacc[((size_t)h * DK + d) * SEQ + rbase + lrow],
                      oT0[dt][rr]);
            atomicAdd(&Oacc[((size_t)h * DK + d) * SEQ + rbase + 16 + lrow],
                      oT1[dt][rr]);
        }
    l0 += __shfl_xor(l0, 16, 64);
    l0 += __shfl_xor(l0, 32, 64);
    l1 += __shfl_xor(l1, 16, 64);
    l1 += __shfl_xor(l1, 32, 64);
    if (quad == 0) {
        atomicAdd(&Lacc[(size_t)h * SEQ + rbase + lrow], l0);
        atomicAdd(&Lacc[(size_t)h * SEQ + rbase + 16 + lrow], l1);
    }
}

// ---------------------------------------------------------------------------
// Ctx[q][h*64+d] = Oacc[h][d][q] / Lacc[h][q]
// ---------------------------------------------------------------------------
__global__ __launch_bounds__(256) void ctx_epilogue(
    const float* __restrict__ Oacc, const float* __restrict__ Lacc,
    bf16_t* __restrict__ Ctx)
{
    const int qt = blockIdx.x;
    const int h  = blockIdx.y;
    const int tid = threadIdx.x;
    __shared__ float T[64][65];

    #pragma unroll
    for (int i = 0; i < 4; i++) {
        int v  = tid + i * 256;
        int d  = v >> 4;
        int qv = v & 15;
        f32x4 o4 = *(const f32x4*)&Oacc[((size_t)h * DK + d) * SEQ + qt * 64 + qv * 4];
        f32x4 l4 = *(const f32x4*)&Lacc[(size_t)h * SEQ + qt * 64 + qv * 4];
        #pragma unroll
        for (int j = 0; j < 4; j++)
            T[qv * 4 + j][d] = o4[j] / l4[j];
    }
    __syncthreads();
    #pragma unroll
    for (int i = 0; i < 2; i++) {
        int v  = tid + i * 256;
        int q  = v >> 3;
        int c8 = v & 7;
        bf16x8 t;
        #pragma unroll
        for (int j = 0; j < 8; j++)
            t[j] = (bf16_t)T[q][c8 * 8 + j];
        *(bf16x8*)&Ctx[(size_t)(qt * 64 + q) * DM + h * DK + c8 * 8] = t;
    }
}

// ---------------------------------------------------------------------------
extern "C" void kernel_launch(void* const* d_in, const int* in_sizes, int n_in,
                              void* d_out, int out_size, void* d_ws, size_t ws_size,
                              hipStream_t stream) {
    const float* x  = (const float*)d_in[0];
    const float* Wq = (const float*)d_in[1];
    const float* bq = (const float*)d_in[2];
    const float* Wk = (const float*)d_in[3];
    const float* bk = (const float*)d_in[4];
    const float* Wv = (const float*)d_in[5];
    const float* bv = (const float*)d_in[6];
    const float* Wo = (const float*)d_in[7];
    const float* bo = (const float*)d_in[8];
    float* out = (float*)d_out;

    const size_t NX = (size_t)SEQ * DM;
    const size_t NW = (size_t)DM * DM;

    bf16_t* xb   = (bf16_t*)d_ws;          // reused as Ctx after flash
    bf16_t* Qb   = xb  + NX;
    bf16_t* Kb   = Qb  + NX;
    bf16_t* Vbt  = Kb  + NX;               // transposed [DM][SEQ]
    bf16_t* Wb   = Vbt + NX;               // Wq,Wk,Wv,Wo bf16
    float*  Oacc = (float*)(Wb + 4 * NW);
    float*  Lacc = Oacc + NX;
    bf16_t* Cx   = xb;

    int cvt_blocks = (int)((NX + 4 * NW) / 4 / 256);
    cvt_bf16<<<cvt_blocks, 256, 0, stream>>>(x, Wq, Wk, Wv, Wo, xb, Wb);
    hipMemsetAsync(Oacc, 0, (NX + (size_t)NH * SEQ) * 4, stream);

    dim3 g1(SEQ / 128, DM / 128, 3);
    gemm_qkv2<<<g1, 256, 0, stream>>>(xb, Wb, bq, bk, bv, Qb, Kb, Vbt);

    // 144 = staircase total for 32 q-tiles of 128 rows (8-k-tile segments)
    dim3 g2(144, 1, NH);
    flash_split6<<<g2, 256, 0, stream>>>(Qb, Kb, Vbt, Oacc, Lacc);

    dim3 g3(SEQ / 64, NH);
    ctx_epilogue<<<g3, 256, 0, stream>>>(Oacc, Lacc, Cx);

    dim3 g4(SEQ / 128, DM / 64);
    gemm_out2<<<g4, 256, 0, stream>>>(Cx, Wb + 3 * NW, bo, out);
}

// Round 6
// 203.975 us; speedup vs baseline: 1.2000x; 1.2000x over previous
//
#include <hip/hip_runtime.h>

#define SEQ 4096
#define DM  768
#define NH  12
#define DK  64

typedef __bf16 bf16_t;
typedef bf16_t bf16x8 __attribute__((ext_vector_type(8)));
typedef bf16_t bf16x4 __attribute__((ext_vector_type(4)));
typedef float  f32x4  __attribute__((ext_vector_type(4)));
typedef short  s16x4  __attribute__((ext_vector_type(4)));

#define LOG2E 1.44269504088896340736f
#define SM_C2 23.0831207f   // 16 * LOG2E; LOG2E folded into K pre-scale

static __device__ inline f32x4 mfma16x16x16_bf16(bf16x4 a, bf16x4 b, f32x4 c) {
#if __has_builtin(__builtin_amdgcn_mfma_f32_16x16x16_bf16)
    return __builtin_amdgcn_mfma_f32_16x16x16_bf16(a, b, c, 0, 0, 0);
#else
    return __builtin_amdgcn_mfma_f32_16x16x16bf16_1k(
        __builtin_bit_cast(s16x4, a), __builtin_bit_cast(s16x4, b), c, 0, 0, 0);
#endif
}

// async global->LDS, 16 B per lane; LDS dest = wave-uniform base + lane*16
static __device__ __forceinline__ void gl_lds16(const bf16_t* g, bf16_t* l) {
    __builtin_amdgcn_global_load_lds(
        (const __attribute__((address_space(1))) void*)g,
        (__attribute__((address_space(3))) void*)l, 16, 0, 0);
}

// ---------------------------------------------------------------------------
// fp32 -> bf16 bulk convert: x (SEQ*DM) then Wq,Wk,Wv,Wo (DM*DM each)
// ---------------------------------------------------------------------------
__global__ __launch_bounds__(256) void cvt_bf16(
    const float* __restrict__ x,  const float* __restrict__ Wq,
    const float* __restrict__ Wk, const float* __restrict__ Wv,
    const float* __restrict__ Wo,
    bf16_t* __restrict__ xb, bf16_t* __restrict__ Wb)
{
    const int NXV = SEQ * DM / 4;
    const int NWV = DM * DM / 4;
    int i4 = blockIdx.x * 256 + threadIdx.x;
    const float* src; bf16_t* dst; int off;
    if (i4 < NXV) { src = x; dst = xb; off = i4; }
    else {
        int j = i4 - NXV;
        int w = j / NWV, jj = j - w * NWV;
        src = (w == 0) ? Wq : (w == 1) ? Wk : (w == 2) ? Wv : Wo;
        dst = Wb + (size_t)w * DM * DM;
        off = jj;
    }
    float4 v = *(const float4*)&src[(size_t)off * 4];
    bf16x4 t;
    t[0] = (bf16_t)v.x; t[1] = (bf16_t)v.y; t[2] = (bf16_t)v.z; t[3] = (bf16_t)v.w;
    *(bf16x4*)&dst[(size_t)off * 4] = t;
}

// ---------------------------------------------------------------------------
// m97-style GEMM (BK=64, global_load_lds 16B, XOR-chunk swizzle).
// C[M,N] = A[M,K](bf16)*W[N,K]^T(bf16)+bias. z = {Q,K,V}; K pre-scaled by
// (1/8)*LOG2E (softmax done in exp2 domain); V stored transposed [DM][SEQ].
// ---------------------------------------------------------------------------
__global__ __launch_bounds__(256) void gemm_qkv2(
    const bf16_t* __restrict__ A, const bf16_t* __restrict__ Wb,
    const float* __restrict__ bq, const float* __restrict__ bk,
    const float* __restrict__ bv,
    bf16_t* __restrict__ Qb, bf16_t* __restrict__ Kb, bf16_t* __restrict__ Vbt)
{
    const int z = blockIdx.z;
    const bf16_t* W = Wb + (size_t)z * DM * DM;
    const float* bias = (z == 0) ? bq : (z == 1) ? bk : bv;

    __shared__ bf16_t As[128][64];   // unpadded (global_load_lds) + swizzle
    __shared__ bf16_t Bs[128][64];

    const int tid  = threadIdx.x;
    const int wave = tid >> 6;
    const int lane = tid & 63;
    const int wm   = wave & 1, wn = wave >> 1;
    const int lrow = lane & 15;
    const int quad = lane >> 4;
    const int row0 = blockIdx.x * 128;
    const int col0 = blockIdx.y * 128;

    const int srow   = lane >> 3;            // 0..7 within 8-row load group
    const int schunk = (lane & 7) ^ srow;    // swizzled source chunk
    const int swz    = lrow & 7;             // frag-read swizzle key

    f32x4 acc[4][4];
    #pragma unroll
    for (int i = 0; i < 4; i++)
        #pragma unroll
        for (int j = 0; j < 4; j++)
            acc[i][j] = (f32x4){0.f, 0.f, 0.f, 0.f};

    for (int k0 = 0; k0 < DM; k0 += 64) {
        __syncthreads();
        #pragma unroll
        for (int u = 0; u < 4; u++) {
            int R0 = wave * 32 + u * 8;
            gl_lds16(&A[(size_t)(row0 + R0 + srow) * DM + k0 + schunk * 8],
                     &As[R0][0]);
            gl_lds16(&W[(size_t)(col0 + R0 + srow) * DM + k0 + schunk * 8],
                     &Bs[R0][0]);
        }
        __syncthreads();   // compiler drains vmcnt here

        #pragma unroll
        for (int s = 0; s < 2; s++) {
            bf16x8 af[4], bfr[4];
            #pragma unroll
            for (int mt = 0; mt < 4; mt++)
                af[mt] = *(const bf16x8*)
                    &As[wm * 64 + mt * 16 + lrow][(((s << 2) | quad) ^ swz) * 8];
            #pragma unroll
            for (int nt = 0; nt < 4; nt++)
                bfr[nt] = *(const bf16x8*)
                    &Bs[wn * 64 + nt * 16 + lrow][(((s << 2) | quad) ^ swz) * 8];
            #pragma unroll
            for (int mt = 0; mt < 4; mt++)
                #pragma unroll
                for (int nt = 0; nt < 4; nt++)
                    acc[mt][nt] = __builtin_amdgcn_mfma_f32_16x16x32_bf16(
                        af[mt], bfr[nt], acc[mt][nt], 0, 0, 0);
        }
    }

    if (z == 2) {          // V transposed [DM][SEQ]
        #pragma unroll
        for (int nt = 0; nt < 4; nt++) {
            int col = col0 + wn * 64 + nt * 16 + lrow;
            float bvv = bias[col];
            #pragma unroll
            for (int mt = 0; mt < 4; mt++) {
                int row = row0 + wm * 64 + mt * 16 + quad * 4;
                bf16x4 t;
                #pragma unroll
                for (int r = 0; r < 4; r++) t[r] = (bf16_t)(acc[mt][nt][r] + bvv);
                *(bf16x4*)&Vbt[(size_t)col * SEQ + row] = t;
            }
        }
    } else {
        bf16_t* Cout = (z == 0) ? Qb : Kb;
        // K: fold 1/sqrt(dk) AND log2(e) so flash softmax is exp2(sc - C)
        float scale = (z == 1) ? (0.125f * LOG2E) : 1.0f;
        #pragma unroll
        for (int nt = 0; nt < 4; nt++) {
            int col = col0 + wn * 64 + nt * 16 + lrow;
            float bvv = bias[col];
            #pragma unroll
            for (int mt = 0; mt < 4; mt++) {
                #pragma unroll
                for (int r = 0; r < 4; r++) {
                    int row = row0 + wm * 64 + mt * 16 + quad * 4 + r;
                    Cout[(size_t)row * DM + col] =
                        (bf16_t)((acc[mt][nt][r] + bvv) * scale);
                }
            }
        }
    }
}

// ---------------------------------------------------------------------------
// out[M,N](f32) = A[M,K](bf16)*W[N,K]^T(bf16)+bias. Tile 128x64 (384 blocks).
// ---------------------------------------------------------------------------
__global__ __launch_bounds__(256) void gemm_out2(
    const bf16_t* __restrict__ A, const bf16_t* __restrict__ W,
    const float* __restrict__ bias, float* __restrict__ C)
{
    __shared__ bf16_t As[128][64];
    __shared__ bf16_t Bs[64][64];

    const int tid  = threadIdx.x;
    const int wave = tid >> 6;
    const int lane = tid & 63;
    const int wm   = wave & 1, wn = wave >> 1;
    const int lrow = lane & 15;
    const int quad = lane >> 4;
    const int row0 = blockIdx.x * 128;
    const int col0 = blockIdx.y * 64;

    const int srow   = lane >> 3;
    const int schunk = (lane & 7) ^ srow;
    const int swz    = lrow & 7;

    f32x4 acc[4][2];
    #pragma unroll
    for (int i = 0; i < 4; i++)
        #pragma unroll
        for (int j = 0; j < 2; j++)
            acc[i][j] = (f32x4){0.f, 0.f, 0.f, 0.f};

    for (int k0 = 0; k0 < DM; k0 += 64) {
        __syncthreads();
        #pragma unroll
        for (int u = 0; u < 4; u++) {
            int R0 = wave * 32 + u * 8;
            gl_lds16(&A[(size_t)(row0 + R0 + srow) * DM + k0 + schunk * 8],
                     &As[R0][0]);
        }
        #pragma unroll
        for (int u = 0; u < 2; u++) {
            int R0 = wave * 16 + u * 8;
            gl_lds16(&W[(size_t)(col0 + R0 + srow) * DM + k0 + schunk * 8],
                     &Bs[R0][0]);
        }
        __syncthreads();

        #pragma unroll
        for (int s = 0; s < 2; s++) {
            bf16x8 af[4], bfr[2];
            #pragma unroll
            for (int mt = 0; mt < 4; mt++)
                af[mt] = *(const bf16x8*)
                    &As[wm * 64 + mt * 16 + lrow][(((s << 2) | quad) ^ swz) * 8];
            #pragma unroll
            for (int nt = 0; nt < 2; nt++)
                bfr[nt] = *(const bf16x8*)
                    &Bs[wn * 32 + nt * 16 + lrow][(((s << 2) | quad) ^ swz) * 8];
            #pragma unroll
            for (int mt = 0; mt < 4; mt++)
                #pragma unroll
                for (int nt = 0; nt < 2; nt++)
                    acc[mt][nt] = __builtin_amdgcn_mfma_f32_16x16x32_bf16(
                        af[mt], bfr[nt], acc[mt][nt], 0, 0, 0);
        }
    }

    #pragma unroll
    for (int nt = 0; nt < 2; nt++) {
        int col = col0 + wn * 32 + nt * 16 + lrow;
        float bvv = bias[col];
        #pragma unroll
        for (int mt = 0; mt < 4; mt++) {
            #pragma unroll
            for (int r = 0; r < 4; r++) {
                int row = row0 + wm * 64 + mt * 16 + quad * 4 + r;
                C[(size_t)row * DM + col] = acc[mt][nt][r] + bvv;
            }
        }
    }
}

// ---------------------------------------------------------------------------
// Flash attention v7 = v5 geometry (proven 70 us: 64-row q-tiles, 4-wave
// blocks, 288-block zombie-free LPT staircase) + v6's proven staging
// mechanism (async global_load_lds, pre-swizzled source, no ds_write):
//
//  - r4 evidence: gl_lds staging cut SQ_LDS_BANK_CONFLICT 6.39M -> 1.6M
//    (75% of v5 conflicts were on the ds_write path) and frees the 16
//    prefetch VGPRs + load->reg->LDS VALU round-trip.
//  - Wave w stages K rows [w*16,w*16+16) and V d-rows [w*16,w*16+16)
//    (2 x 1KB gl_lds16 each); source pointers advanced by +64*DM / +64
//    per k-tile (2 pointer adds/iter instead of full address recompute).
//  - One barrier per iter: barrier drains vmcnt (buf b ready), then issue
//    STAGE(b^1, kt+1) whose latency hides under compute on buf b.
//
// K pre-scaled by (1/8)*LOG2E; fixed-shift exp2 softmax; partials additive
// -> fp32 atomics into Oacc/Lacc.
// ---------------------------------------------------------------------------
__global__ __launch_bounds__(256) void flash_split7(
    const bf16_t* __restrict__ Qb, const bf16_t* __restrict__ Kb,
    const bf16_t* __restrict__ Vbt,
    float* __restrict__ Oacc /* [NH][DK][SEQ] */,
    float* __restrict__ Lacc /* [NH][SEQ] */)
{
    const int h = blockIdx.z;
    const int f = 287 - blockIdx.x;     // longest-first (LPT)
    int g = 0;                          // staircase group = qi/8
    while (f >= 4 * (g + 1) * (g + 2)) g++;
    const int rem = f - 4 * g * (g + 1);
    const int qs  = rem / (g + 1);
    const int seg = rem - qs * (g + 1);
    const int qi  = g * 8 + qs;         // q-tile (64 rows)
    const int q0  = qi << 6;
    const int kt0    = seg << 3;        // first k-tile (64 keys each)
    const int ktlast = min(kt0 + 7, qi);

    const int tid  = threadIdx.x;
    const int wave = tid >> 6;          // 0..3, owns rows q0+wave*16..+15
    const int lane = tid & 63;
    const int lrow = lane & 15;
    const int quad = lane >> 4;
    const int swz  = lrow & 7;

    __shared__ bf16_t Ks[2][64][64];    // [key][kdim], XOR-swizzled chunks
    __shared__ bf16_t Vs[2][64][64];    // [d][key],   XOR-swizzled chunks

    const int qrow = q0 + wave * 16 + lrow;
    bf16x8 qfrag[2];
    #pragma unroll
    for (int s = 0; s < 2; s++)
        qfrag[s] = *(const bf16x8*)&Qb[(size_t)qrow * DM + h * DK + s * 32 + quad * 8];

    f32x4 oT[4];
    #pragma unroll
    for (int dt = 0; dt < 4; dt++) oT[dt] = (f32x4){0.f, 0.f, 0.f, 0.f};
    float l_i = 0.f;

    // staging (v6-proven): wave w stages K rows w*16..+15, V d-rows w*16..+15
    const int srow8 = lane >> 3;              // 0..7 within 8-row group
    const int schnk = (lane & 7) ^ srow8;     // pre-swizzled source chunk

    size_t ko = (size_t)kt0 << 6;
    const bf16_t* kp = Kb  + (ko + wave * 16 + srow8) * DM + h * DK + schnk * 8;
    const bf16_t* vp = Vbt + ((size_t)(h * DK + wave * 16 + srow8)) * SEQ
                           + ko + schnk * 8;

    #define STAGE(bb)                                                          \
        do {                                                                   \
            gl_lds16(kp,            &Ks[bb][wave * 16][0]);                    \
            gl_lds16(kp + 8 * DM,   &Ks[bb][wave * 16 + 8][0]);                \
            gl_lds16(vp,            &Vs[bb][wave * 16][0]);                    \
            gl_lds16(vp + 8 * SEQ,  &Vs[bb][wave * 16 + 8][0]);                \
            kp += 64 * DM;                                                     \
            vp += 64;                                                          \
        } while (0)

    STAGE(0);

    for (int kt = kt0; kt <= ktlast; kt++) {
        const int b = kt & 1;
        __syncthreads();                // drains vmcnt -> buf b ready
        if (kt < ktlast) STAGE(b ^ 1);  // latency hides under compute

        f32x4 sc[4];
        #pragma unroll
        for (int mt = 0; mt < 4; mt++) {
            f32x4 a = (f32x4){0.f, 0.f, 0.f, 0.f};
            #pragma unroll
            for (int s = 0; s < 2; s++) {
                bf16x8 kf = *(const bf16x8*)
                    &Ks[b][mt * 16 + lrow][(((s << 2) | quad) ^ swz) * 8];
                a = __builtin_amdgcn_mfma_f32_16x16x32_bf16(kf, qfrag[s], a, 0, 0, 0);
            }
            sc[mt] = a;
        }

        if (kt == qi) {                 // causal mask, diagonal tile only
            #pragma unroll
            for (int mt = 0; mt < 4; mt++)
                #pragma unroll
                for (int rr = 0; rr < 4; rr++)
                    if ((kt << 6) + mt * 16 + quad * 4 + rr > qrow)
                        sc[mt][rr] = -1e30f;
        }

        bf16x4 pf[4];
        float rsum = 0.f;
        #pragma unroll
        for (int mt = 0; mt < 4; mt++) {
            bf16x4 t;
            #pragma unroll
            for (int rr = 0; rr < 4; rr++) {
                float p = __builtin_amdgcn_exp2f(sc[mt][rr] - SM_C2);
                rsum += p;
                t[rr] = (bf16_t)p;
            }
            pf[mt] = t;
        }
        l_i += rsum;

        #pragma unroll
        for (int dt = 0; dt < 4; dt++)
            #pragma unroll
            for (int kb = 0; kb < 4; kb++) {
                // logical 8B chunk 2*kb+(quad>>1) -> phys 16B chunk ^ swz
                int c16 = (kb * 2 + (quad >> 1)) ^ swz;
                bf16x4 vf = *(const bf16x4*)
                    &Vs[b][dt * 16 + lrow][c16 * 8 + (quad & 1) * 4];
                oT[dt] = mfma16x16x16_bf16(vf, pf[kb], oT[dt]);
            }
    }
    #undef STAGE

    #pragma unroll
    for (int dt = 0; dt < 4; dt++)
        #pragma unroll
        for (int rr = 0; rr < 4; rr++) {
            int d = dt * 16 + quad * 4 + rr;
            atomicAdd(&Oacc[((size_t)h * DK + d) * SEQ + qrow], oT[dt][rr]);
        }
    l_i += __shfl_xor(l_i, 16, 64);
    l_i += __shfl_xor(l_i, 32, 64);
    if (quad == 0)
        atomicAdd(&Lacc[(size_t)h * SEQ + qrow], l_i);
}

// ---------------------------------------------------------------------------
// Ctx[q][h*64+d] = Oacc[h][d][q] / Lacc[h][q]
// ---------------------------------------------------------------------------
__global__ __launch_bounds__(256) void ctx_epilogue(
    const float* __restrict__ Oacc, const float* __restrict__ Lacc,
    bf16_t* __restrict__ Ctx)
{
    const int qt = blockIdx.x;
    const int h  = blockIdx.y;
    const int tid = threadIdx.x;
    __shared__ float T[64][65];

    #pragma unroll
    for (int i = 0; i < 4; i++) {
        int v  = tid + i * 256;
        int d  = v >> 4;
        int qv = v & 15;
        f32x4 o4 = *(const f32x4*)&Oacc[((size_t)h * DK + d) * SEQ + qt * 64 + qv * 4];
        f32x4 l4 = *(const f32x4*)&Lacc[(size_t)h * SEQ + qt * 64 + qv * 4];
        #pragma unroll
        for (int j = 0; j < 4; j++)
            T[qv * 4 + j][d] = o4[j] / l4[j];
    }
    __syncthreads();
    #pragma unroll
    for (int i = 0; i < 2; i++) {
        int v  = tid + i * 256;
        int q  = v >> 3;
        int c8 = v & 7;
        bf16x8 t;
        #pragma unroll
        for (int j = 0; j < 8; j++)
            t[j] = (bf16_t)T[q][c8 * 8 + j];
        *(bf16x8*)&Ctx[(size_t)(qt * 64 + q) * DM + h * DK + c8 * 8] = t;
    }
}

// ---------------------------------------------------------------------------
extern "C" void kernel_launch(void* const* d_in, const int* in_sizes, int n_in,
                              void* d_out, int out_size, void* d_ws, size_t ws_size,
                              hipStream_t stream) {
    const float* x  = (const float*)d_in[0];
    const float* Wq = (const float*)d_in[1];
    const float* bq = (const float*)d_in[2];
    const float* Wk = (const float*)d_in[3];
    const float* bk = (const float*)d_in[4];
    const float* Wv = (const float*)d_in[5];
    const float* bv = (const float*)d_in[6];
    const float* Wo = (const float*)d_in[7];
    const float* bo = (const float*)d_in[8];
    float* out = (float*)d_out;

    const size_t NX = (size_t)SEQ * DM;
    const size_t NW = (size_t)DM * DM;

    bf16_t* xb   = (bf16_t*)d_ws;          // reused as Ctx after flash
    bf16_t* Qb   = xb  + NX;
    bf16_t* Kb   = Qb  + NX;
    bf16_t* Vbt  = Kb  + NX;               // transposed [DM][SEQ]
    bf16_t* Wb   = Vbt + NX;               // Wq,Wk,Wv,Wo bf16
    float*  Oacc = (float*)(Wb + 4 * NW);
    float*  Lacc = Oacc + NX;
    bf16_t* Cx   = xb;

    int cvt_blocks = (int)((NX + 4 * NW) / 4 / 256);
    cvt_bf16<<<cvt_blocks, 256, 0, stream>>>(x, Wq, Wk, Wv, Wo, xb, Wb);
    hipMemsetAsync(Oacc, 0, (NX + (size_t)NH * SEQ) * 4, stream);

    dim3 g1(SEQ / 128, DM / 128, 3);
    gemm_qkv2<<<g1, 256, 0, stream>>>(xb, Wb, bq, bk, bv, Qb, Kb, Vbt);

    // 288 = staircase total for 64 q-tiles of 64 rows (8-k-tile segments)
    dim3 g2(288, 1, NH);
    flash_split7<<<g2, 256, 0, stream>>>(Qb, Kb, Vbt, Oacc, Lacc);

    dim3 g3(SEQ / 64, NH);
    ctx_epilogue<<<g3, 256, 0, stream>>>(Oacc, Lacc, Cx);

    dim3 g4(SEQ / 128, DM / 64);
    gemm_out2<<<g4, 256, 0, stream>>>(Cx, Wb + 3 * NW, bo, out);
}